// Round 2
// baseline (4454.657 us; speedup 1.0000x reference)
//
#include <hip/hip_runtime.h>
#include <hip/hip_bf16.h>
#include <math.h>

typedef unsigned short u16;
typedef __attribute__((ext_vector_type(8))) short bf16x8;
typedef __attribute__((ext_vector_type(4))) float f32x4;

#define IN_CH   256
#define STATE   384
#define OUT_SEQ 32
#define B_SZ    8
#define SEQ     512
#define M_ROWS  4096
#define NJ      768   // 2*STATE, virtual K of Z / N of U

// ---------------- workspace layout (bytes) ----------------
static constexpr size_t SZ_ZP  = (size_t)M_ROWS*NJ*2;      // one Z split plane
static constexpr size_t SZ_XP  = (size_t)M_ROWS*IN_CH*2;   // one X split plane
static constexpr size_t SZ_WBP = (size_t)NJ*IN_CH*2;       // WBt plane [768][256]
static constexpr size_t SZ_WCP = (size_t)IN_CH*NJ*2;       // WCt plane [256][768]
static constexpr size_t SZ_WDP = (size_t)IN_CH*IN_CH*2;    // WDt plane [256][256]
static constexpr size_t B_U   = 0;                          // U fp32 [4096][768]
static constexpr size_t B_Z   = B_U  + (size_t)M_ROWS*NJ*4;
static constexpr size_t B_XA  = B_Z  + 3*SZ_ZP;
static constexpr size_t B_XB  = B_XA + 3*SZ_XP;
static constexpr size_t B_WB  = B_XB + 3*SZ_XP;
static constexpr size_t B_WC  = B_WB + 3*SZ_WBP;
static constexpr size_t B_WD  = B_WC + 3*SZ_WCP;
static constexpr size_t B_LAM = B_WD + 3*SZ_WDP;
static constexpr size_t B_HC  = B_LAM + 768*4;
// total ~46.9 MB

// ---------------- helpers ----------------
__device__ __forceinline__ u16 f2b(float v) {
    __hip_bfloat16 h = __float2bfloat16(v);
    return *(u16*)&h;
}
__device__ __forceinline__ float b2f(u16 u) {
    __hip_bfloat16 h = *(__hip_bfloat16*)&u;
    return __bfloat162float(h);
}
__device__ __forceinline__ void split3(float v, u16& a, u16& b, u16& c) {
    a = f2b(v);  float r1 = v  - b2f(a);
    b = f2b(r1); float r2 = r1 - b2f(b);
    c = f2b(r2);
}
__device__ __forceinline__ void gload_lds16(const void* g, void* l) {
    __builtin_amdgcn_global_load_lds(
        (const __attribute__((address_space(1))) void*)g,
        (__attribute__((address_space(3))) void*)l, 16, 0, 0);
}

// ---------------- prep kernels ----------------
__global__ void prep_lam_hc(const float* __restrict__ nu_log,
                            const float* __restrict__ th_log,
                            float* __restrict__ lam, float* __restrict__ hc) {
    int n = threadIdx.x;
    if (n < STATE) {
        float lm = expf(-expf(nu_log[n]));
        float th = expf(th_log[n]);
        lam[2*n]   = lm * cosf(th);
        lam[2*n+1] = lm * sinf(th);
    }
    for (int i = threadIdx.x; i < B_SZ*NJ; i += blockDim.x) hc[i] = 0.f;
}

// WBt[p][j][c] = split_p(gamma_n * B_{re/im}[n][c]), j = 2n+f  (transposed: [768][256])
__global__ void prep_wb(const float* __restrict__ B_re, const float* __restrict__ B_im,
                        const float* __restrict__ gamma_log, u16* __restrict__ W) {
    int idx = blockIdx.x*blockDim.x + threadIdx.x;   // < 768*256
    int j = idx >> 8, c = idx & 255, n = j >> 1;
    float g = expf(gamma_log[n]);
    float v = g * ((j & 1) ? B_im[n*IN_CH + c] : B_re[n*IN_CH + c]);
    u16 a,b,cc; split3(v,a,b,cc);
    W[idx] = a; W[idx + NJ*IN_CH] = b; W[idx + 2*NJ*IN_CH] = cc;
}

// WCt[p][o][j] = split_p(j&1 ? -C_im[o][n] : C_re[o][n]); WDt[p][o][c] = split_p(D[o][c])
__global__ void prep_wcd(const float* __restrict__ C_re, const float* __restrict__ C_im,
                         const float* __restrict__ D,
                         u16* __restrict__ WC, u16* __restrict__ WD) {
    int idx = blockIdx.x*blockDim.x + threadIdx.x;   // < 256*768 + 256*256
    if (idx < IN_CH*NJ) {
        int o = idx / NJ, j = idx % NJ, n = j >> 1;
        float v = (j & 1) ? -C_im[o*STATE + n] : C_re[o*STATE + n];
        u16 a,b,c; split3(v,a,b,c);
        WC[idx] = a; WC[idx + IN_CH*NJ] = b; WC[idx + 2*IN_CH*NJ] = c;
    } else {
        int k = idx - IN_CH*NJ;
        float v = D[k];   // D already [o][c]
        u16 a,b,c; split3(v,a,b,c);
        WD[k] = a; WD[k + IN_CH*IN_CH] = b; WD[k + 2*IN_CH*IN_CH] = c;
    }
}

__global__ void prep_x(const float* __restrict__ x,
                       u16* __restrict__ X1, u16* __restrict__ X2, u16* __restrict__ X3) {
    int idx = blockIdx.x*blockDim.x + threadIdx.x;   // < 4096*256
    u16 a,b,c; split3(x[idx],a,b,c);
    X1[idx] = a; X2[idx] = b; X3[idx] = c;
}

// ---------------- scan ----------------
#define PF 16
__global__ __launch_bounds__(64)
void scan_k(const float* __restrict__ Uf,
            u16* __restrict__ Z1, u16* __restrict__ Z2, u16* __restrict__ Z3,
            const float* __restrict__ lam, float* __restrict__ Hc) {
    int b = blockIdx.x / 6, g = blockIdx.x % 6;
    int n = g*64 + threadIdx.x;
    float lre = lam[2*n], lim = lam[2*n+1];
    float hre = Hc[b*NJ + 2*n], him = Hc[b*NJ + 2*n + 1];
    const float2* U2 = (const float2*)Uf + (size_t)b*SEQ*STATE + n;
    size_t zb = (size_t)b*SEQ*NJ + 2*n;
    float2 buf[PF];
#pragma unroll
    for (int p = 0; p < PF; ++p) buf[p] = U2[(size_t)p*STATE];
    for (int s0 = 0; s0 < SEQ; s0 += PF) {
#pragma unroll
        for (int p = 0; p < PF; ++p) {
            int s = s0 + p;
            float ur = buf[p].x, ui = buf[p].y;
            if (s + PF < SEQ) buf[p] = U2[(size_t)(s+PF)*STATE];
            float nr = fmaf(lre, hre, fmaf(-lim, him, ur));
            float ni = fmaf(lre, him, fmaf( lim, hre, ui));
            hre = nr; him = ni;
            u16 a1,a2,a3, c1,c2,c3;
            split3(nr, a1,a2,a3);
            split3(ni, c1,c2,c3);
            size_t zo = zb + (size_t)s*NJ;
            ushort2 t;
            t.x = a1; t.y = c1; *(ushort2*)(Z1 + zo) = t;
            t.x = a2; t.y = c2; *(ushort2*)(Z2 + zo) = t;
            t.x = a3; t.y = c3; *(ushort2*)(Z3 + zo) = t;
        }
    }
    Hc[b*NJ + 2*n] = hre; Hc[b*NJ + 2*n + 1] = him;
}

// ---------------- MFMA GEMM over segment list ----------------
// C[M][BN-tile] += sum_seg A_seg[M][K] * B_seg^T, B stored transposed [n][k].
// Both operands row-major with row stride == K. BK=32, 256 threads (4 waves).
struct Seg { const u16* A; const u16* B; int K; };
struct SegList { Seg s[12]; int n; };

template<int BM, int WR, int WC, bool TO_U>
__global__ __launch_bounds__(256)
void gemm_mfma(SegList segs, float* __restrict__ Uout,
               u16* __restrict__ O1, u16* __restrict__ O2, u16* __restrict__ O3,
               float* __restrict__ outp, int iter) {
    constexpr int BN = 64, BK = 32;
    constexpr int FM = BM/(WR*16), FN = BN/(WC*16);
    constexpr int ACH = BM*4, TCH = (BM+BN)*4;   // 16B chunks
    __shared__ __align__(16) char smem[(size_t)(BM+BN)*64];
    const int tid = threadIdx.x;
    const int lane = tid & 63, w = tid >> 6;
    const int wr = w % WR, wc = w / WR;
    const int m0 = blockIdx.x * BM, n0 = blockIdx.y * BN;

    f32x4 acc[FM][FN];
#pragma unroll
    for (int i = 0; i < FM; ++i)
#pragma unroll
        for (int j = 0; j < FN; ++j) acc[i][j] = 0.f;

    // LDS read offsets (XOR-swizzled: slot ^= row&3 within each 64B row)
    int aoff[FM], boff[FN];
#pragma unroll
    for (int i = 0; i < FM; ++i) {
        int row = wr*(BM/WR) + i*16 + (lane & 15);
        aoff[i] = row*64 + ((((lane >> 4) ^ (row & 3))) << 4);
    }
#pragma unroll
    for (int j = 0; j < FN; ++j) {
        int row = wc*(BN/WC) + j*16 + (lane & 15);
        boff[j] = BM*64 + row*64 + ((((lane >> 4) ^ (row & 3))) << 4);
    }

    for (int sg = 0; sg < segs.n; ++sg) {
        const u16* Ap = segs.s[sg].A;
        const u16* Bp = segs.s[sg].B;
        const int  K  = segs.s[sg].K;
        for (int k0 = 0; k0 < K; k0 += BK) {
            // stage: LDS linear, global source pre-swizzled (m173 pattern)
#pragma unroll
            for (int r = 0; r < (TCH + 255)/256; ++r) {
                int q = tid + r*256;
                if (TCH % 256 == 0 || q < TCH) {
                    const u16* gsrc;
                    if (q < ACH) {
                        int row = q >> 2, slot = q & 3;
                        gsrc = Ap + (size_t)(m0 + row)*K + k0 + ((slot ^ (row & 3)) << 3);
                    } else {
                        int q2 = q - ACH;
                        int row = q2 >> 2, slot = q2 & 3;
                        gsrc = Bp + (size_t)(n0 + row)*K + k0 + ((slot ^ (row & 3)) << 3);
                    }
                    gload_lds16(gsrc, smem + (size_t)q*16);
                }
            }
            __syncthreads();
            bf16x8 av[FM], bv[FN];
#pragma unroll
            for (int i = 0; i < FM; ++i) av[i] = *(const bf16x8*)(smem + aoff[i]);
#pragma unroll
            for (int j = 0; j < FN; ++j) bv[j] = *(const bf16x8*)(smem + boff[j]);
#pragma unroll
            for (int i = 0; i < FM; ++i)
#pragma unroll
                for (int j = 0; j < FN; ++j)
                    acc[i][j] = __builtin_amdgcn_mfma_f32_16x16x32_bf16(
                        av[i], bv[j], acc[i][j], 0, 0, 0);
            __syncthreads();
        }
    }

    // epilogue: D layout n = lane&15, m = (lane>>4)*4 + q
#pragma unroll
    for (int i = 0; i < FM; ++i) {
        int rb = m0 + wr*(BM/WR) + i*16 + ((lane >> 4) << 2);
#pragma unroll
        for (int j = 0; j < FN; ++j) {
            int col = n0 + wc*(BN/WC) + j*16 + (lane & 15);
#pragma unroll
            for (int q = 0; q < 4; ++q) {
                int row = rb + q;
                float v = acc[i][j][q];
                if (TO_U) {
                    Uout[(size_t)row*NJ + col] = v;
                } else {
                    u16 h1,h2,h3; split3(v, h1,h2,h3);
                    size_t o = (size_t)row*IN_CH + col;
                    O1[o] = h1; O2[o] = h2; O3[o] = h3;
                    if ((row & (SEQ-1)) == SEQ-1)
                        outp[(size_t)((row >> 9)*OUT_SEQ + iter)*IN_CH + col] = v;
                }
            }
        }
    }
}

// ---------------- launch ----------------
extern "C" void kernel_launch(void* const* d_in, const int* in_sizes, int n_in,
                              void* d_out, int out_size, void* d_ws, size_t ws_size,
                              hipStream_t stream) {
    const float* x_in      = (const float*)d_in[0];
    const float* nu_log    = (const float*)d_in[1];
    const float* theta_log = (const float*)d_in[2];
    const float* gamma_log = (const float*)d_in[3];
    const float* B_re      = (const float*)d_in[4];
    const float* B_im      = (const float*)d_in[5];
    const float* C_re      = (const float*)d_in[6];
    const float* C_im      = (const float*)d_in[7];
    const float* D         = (const float*)d_in[8];
    float* out = (float*)d_out;

    char* ws = (char*)d_ws;
    float* U   = (float*)(ws + B_U);
    u16* Z1 = (u16*)(ws + B_Z);
    u16* Z2 = Z1 + M_ROWS*NJ;
    u16* Z3 = Z2 + M_ROWS*NJ;
    u16* XA1 = (u16*)(ws + B_XA);
    u16* XA2 = XA1 + M_ROWS*IN_CH;
    u16* XA3 = XA2 + M_ROWS*IN_CH;
    u16* XB1 = (u16*)(ws + B_XB);
    u16* XB2 = XB1 + M_ROWS*IN_CH;
    u16* XB3 = XB2 + M_ROWS*IN_CH;
    u16* WB  = (u16*)(ws + B_WB);   // 3 planes of [768][256]
    u16* WCt = (u16*)(ws + B_WC);   // 3 planes of [256][768]
    u16* WDt = (u16*)(ws + B_WD);   // 3 planes of [256][256]
    float* lam = (float*)(ws + B_LAM);
    float* Hc  = (float*)(ws + B_HC);

    prep_lam_hc<<<1, 384, 0, stream>>>(nu_log, theta_log, lam, Hc);
    prep_wb<<<(NJ*IN_CH)/256, 256, 0, stream>>>(B_re, B_im, gamma_log, WB);
    prep_wcd<<<(IN_CH*NJ + IN_CH*IN_CH)/256, 256, 0, stream>>>(C_re, C_im, D, WCt, WDt);
    prep_x<<<(M_ROWS*IN_CH)/256, 256, 0, stream>>>(x_in, XA1, XA2, XA3);

    // 6-product bf16x3 pair order, large terms first
    static const int PI[6] = {0,0,1,0,1,2};
    static const int PJ[6] = {0,1,0,2,1,0};

    for (int it = 0; it < OUT_SEQ; ++it) {
        u16* Xc[3]; u16* Xn[3];
        if (it & 1) { Xc[0]=XB1; Xc[1]=XB2; Xc[2]=XB3; Xn[0]=XA1; Xn[1]=XA2; Xn[2]=XA3; }
        else        { Xc[0]=XA1; Xc[1]=XA2; Xc[2]=XA3; Xn[0]=XB1; Xn[1]=XB2; Xn[2]=XB3; }

        // GEMM1: U[4096][768] = sum_p Xc_i * WBt_j   (K=256 per segment)
        SegList g1; g1.n = 6;
        for (int t = 0; t < 6; ++t) {
            g1.s[t].A = Xc[PI[t]];
            g1.s[t].B = WB + (size_t)PJ[t]*NJ*IN_CH;
            g1.s[t].K = IN_CH;
        }
        gemm_mfma<64,2,2,true><<<dim3(M_ROWS/64, NJ/64), 256, 0, stream>>>(
            g1, U, nullptr, nullptr, nullptr, nullptr, 0);

        // scan: Z splits = scan(U)
        scan_k<<<48, 64, 0, stream>>>(U, Z1, Z2, Z3, lam, Hc);

        // GEMM2: Xn[4096][256] = sum_p Z_i*WCt_j (K=768) + sum_p Xc_i*WDt_j (K=256)
        u16* Zp[3] = {Z1, Z2, Z3};
        SegList g2; g2.n = 12;
        for (int t = 0; t < 6; ++t) {
            g2.s[t].A = Zp[PI[t]];
            g2.s[t].B = WCt + (size_t)PJ[t]*IN_CH*NJ;
            g2.s[t].K = NJ;
            g2.s[6+t].A = Xc[PI[t]];
            g2.s[6+t].B = WDt + (size_t)PJ[t]*IN_CH*IN_CH;
            g2.s[6+t].K = IN_CH;
        }
        gemm_mfma<32,1,4,false><<<dim3(M_ROWS/32, IN_CH/64), 256, 0, stream>>>(
            g2, nullptr, Xn[0], Xn[1], Xn[2], out, it);
    }
}

// Round 3
// 3594.073 us; speedup vs baseline: 1.2394x; 1.2394x over previous
//
#include <hip/hip_runtime.h>
#include <hip/hip_bf16.h>
#include <math.h>

typedef unsigned short u16;
typedef __attribute__((ext_vector_type(8))) short bf16x8;
typedef __attribute__((ext_vector_type(4))) float f32x4;

#define IN_CH   256
#define STATE   384
#define OUT_SEQ 32
#define B_SZ    8
#define SEQ     512
#define M_ROWS  4096
#define NJ      768   // 2*STATE

// ---------------- workspace layout (bytes) ----------------
static constexpr size_t SZ_ZP  = (size_t)M_ROWS*NJ*2;
static constexpr size_t SZ_XP  = (size_t)M_ROWS*IN_CH*2;
static constexpr size_t SZ_WBP = (size_t)NJ*IN_CH*2;
static constexpr size_t SZ_WCP = (size_t)IN_CH*NJ*2;
static constexpr size_t SZ_WDP = (size_t)IN_CH*IN_CH*2;
static constexpr size_t B_U   = 0;
static constexpr size_t B_Z   = B_U  + (size_t)M_ROWS*NJ*4;
static constexpr size_t B_XA  = B_Z  + 3*SZ_ZP;
static constexpr size_t B_XB  = B_XA + 3*SZ_XP;
static constexpr size_t B_WB  = B_XB + 3*SZ_XP;
static constexpr size_t B_WC  = B_WB + 3*SZ_WBP;
static constexpr size_t B_WD  = B_WC + 3*SZ_WCP;
static constexpr size_t B_LAM = B_WD + 3*SZ_WDP;
static constexpr size_t B_HC  = B_LAM + 768*4;

// ---------------- helpers ----------------
__device__ __forceinline__ u16 f2b(float v) {
    __hip_bfloat16 h = __float2bfloat16(v);
    return *(u16*)&h;
}
__device__ __forceinline__ float b2f(u16 u) {
    __hip_bfloat16 h = *(__hip_bfloat16*)&u;
    return __bfloat162float(h);
}
__device__ __forceinline__ void split3(float v, u16& a, u16& b, u16& c) {
    a = f2b(v);  float r1 = v  - b2f(a);
    b = f2b(r1); float r2 = r1 - b2f(b);
    c = f2b(r2);
}
__device__ __forceinline__ void gload_lds16(const void* g, void* l) {
    __builtin_amdgcn_global_load_lds(
        (const __attribute__((address_space(1))) void*)g,
        (__attribute__((address_space(3))) void*)l, 16, 0, 0);
}

// ---------------- prep kernels ----------------
__global__ void prep_lam_hc(const float* __restrict__ nu_log,
                            const float* __restrict__ th_log,
                            float* __restrict__ lam, float* __restrict__ hc) {
    int n = threadIdx.x;
    if (n < STATE) {
        float lm = expf(-expf(nu_log[n]));
        float th = expf(th_log[n]);
        lam[2*n]   = lm * cosf(th);
        lam[2*n+1] = lm * sinf(th);
    }
    for (int i = threadIdx.x; i < B_SZ*NJ; i += blockDim.x) hc[i] = 0.f;
}

__global__ void prep_wb(const float* __restrict__ B_re, const float* __restrict__ B_im,
                        const float* __restrict__ gamma_log, u16* __restrict__ W) {
    int idx = blockIdx.x*blockDim.x + threadIdx.x;   // < 768*256
    int j = idx >> 8, c = idx & 255, n = j >> 1;
    float g = expf(gamma_log[n]);
    float v = g * ((j & 1) ? B_im[n*IN_CH + c] : B_re[n*IN_CH + c]);
    u16 a,b,cc; split3(v,a,b,cc);
    W[idx] = a; W[idx + NJ*IN_CH] = b; W[idx + 2*NJ*IN_CH] = cc;
}

__global__ void prep_wcd(const float* __restrict__ C_re, const float* __restrict__ C_im,
                         const float* __restrict__ D,
                         u16* __restrict__ WC, u16* __restrict__ WD) {
    int idx = blockIdx.x*blockDim.x + threadIdx.x;
    if (idx < IN_CH*NJ) {
        int o = idx / NJ, j = idx % NJ, n = j >> 1;
        float v = (j & 1) ? -C_im[o*STATE + n] : C_re[o*STATE + n];
        u16 a,b,c; split3(v,a,b,c);
        WC[idx] = a; WC[idx + IN_CH*NJ] = b; WC[idx + 2*IN_CH*NJ] = c;
    } else {
        int k = idx - IN_CH*NJ;
        float v = D[k];
        u16 a,b,c; split3(v,a,b,c);
        WD[k] = a; WD[k + IN_CH*IN_CH] = b; WD[k + 2*IN_CH*IN_CH] = c;
    }
}

__global__ void prep_x(const float* __restrict__ x,
                       u16* __restrict__ X1, u16* __restrict__ X2, u16* __restrict__ X3) {
    int idx = blockIdx.x*blockDim.x + threadIdx.x;
    u16 a,b,c; split3(x[idx],a,b,c);
    X1[idx] = a; X2[idx] = b; X3[idx] = c;
}

// ---------------- scan ----------------
#define PF 64
__global__ __launch_bounds__(64)
void scan_k(const float* __restrict__ Uf,
            u16* __restrict__ Z1, u16* __restrict__ Z2, u16* __restrict__ Z3,
            const float* __restrict__ lam, float* __restrict__ Hc) {
    int b = blockIdx.x / 6, g = blockIdx.x % 6;
    int n = g*64 + threadIdx.x;
    float lre = lam[2*n], lim = lam[2*n+1];
    float hre = Hc[b*NJ + 2*n], him = Hc[b*NJ + 2*n + 1];
    const float2* U2 = (const float2*)Uf + (size_t)b*SEQ*STATE + n;
    size_t zb = (size_t)b*SEQ*NJ + 2*n;
    float2 buf[PF];
#pragma unroll
    for (int p = 0; p < PF; ++p) buf[p] = U2[(size_t)p*STATE];
    for (int s0 = 0; s0 < SEQ; s0 += PF) {
#pragma unroll
        for (int p = 0; p < PF; ++p) {
            int s = s0 + p;
            float ur = buf[p].x, ui = buf[p].y;
            if (s + PF < SEQ) buf[p] = U2[(size_t)(s+PF)*STATE];
            float nr = fmaf(lre, hre, fmaf(-lim, him, ur));
            float ni = fmaf(lre, him, fmaf( lim, hre, ui));
            hre = nr; him = ni;
            u16 a1,a2,a3, c1,c2,c3;
            split3(nr, a1,a2,a3);
            split3(ni, c1,c2,c3);
            size_t zo = zb + (size_t)s*NJ;
            ushort2 t;
            t.x = a1; t.y = c1; *(ushort2*)(Z1 + zo) = t;
            t.x = a2; t.y = c2; *(ushort2*)(Z2 + zo) = t;
            t.x = a3; t.y = c3; *(ushort2*)(Z3 + zo) = t;
        }
    }
    Hc[b*NJ + 2*n] = hre; Hc[b*NJ + 2*n + 1] = him;
}

// ---------------- fused triple-plane MFMA GEMM ----------------
// Virtual product: C = sum over 6 plane-pairs of A_pi * B_pj^T, accumulated in fp32.
// Two K-segments (S2 may be 0). B stored transposed [n][k], row stride = K.
// BK=32. 2-phase double-buffered pipeline, one barrier per k-step.
struct GArgs {
    const u16* A1[3]; const u16* B1[3];
    const u16* A2[3]; const u16* B2[3];
};

template<int BM, int BN, int WR, int WC, int S1, int S2, bool TO_U>
__global__ __launch_bounds__(256)
void gemm3(GArgs ga, float* __restrict__ Uout,
           u16* __restrict__ O1, u16* __restrict__ O2, u16* __restrict__ O3,
           float* __restrict__ outp, int iter) {
    constexpr int FM = BM/(WR*16), FN = BN/(WC*16);
    constexpr int PA = BM*64, PB = BN*64;      // LDS plane bytes (row = 32 bf16 = 64B)
    constexpr int SBUF = 3*(PA+PB);
    constexpr int CA = 3*BM*4, CT = 3*(BM+BN)*4;   // 16B chunks
    constexpr int NT = S1 + S2;
    __shared__ __align__(16) char smem[2*SBUF];
    const int tid = threadIdx.x, lane = tid & 63, w = tid >> 6;
    const int wr = w % WR, wc = w / WR;
    const int m0 = blockIdx.x*BM, n0 = blockIdx.y*BN;
    const int hi = lane >> 4;

    f32x4 acc[FM][FN];
#pragma unroll
    for (int i = 0; i < FM; ++i)
#pragma unroll
        for (int j = 0; j < FN; ++j) acc[i][j] = 0.f;

    // ds_read offsets: slot = hi ^ ((row>>1)&3)  (conflict-free for 64B rows)
    int aoff[3][FM], boff[3][FN];
#pragma unroll
    for (int p = 0; p < 3; ++p) {
#pragma unroll
        for (int i = 0; i < FM; ++i) {
            int row = wr*(BM/WR) + i*16 + (lane & 15);
            aoff[p][i] = p*PA + row*64 + ((hi ^ ((row>>1)&3)) << 4);
        }
#pragma unroll
        for (int j = 0; j < FN; ++j) {
            int row = wc*(BN/WC) + j*16 + (lane & 15);
            boff[p][j] = 3*PA + p*PB + row*64 + ((hi ^ ((row>>1)&3)) << 4);
        }
    }

    auto stage = [&](int t, int buf) {
        const u16* const* Ap = ga.A1;
        const u16* const* Bp = ga.B1;
        int K = S1*32, k0 = t*32;
        if (S2 != 0 && t >= S1) { Ap = ga.A2; Bp = ga.B2; K = S2*32; k0 = (t - S1)*32; }
        char* L = smem + (size_t)buf*SBUF;
#pragma unroll
        for (int r = 0; r < (CT + 255)/256; ++r) {
            int q = tid + r*256;
            if (CT % 256 == 0 || q < CT) {
                const u16* gsrc;
                if (q < CA) {
                    int p = q / (BM*4), qq = q % (BM*4);
                    int row = qq >> 2, slot = qq & 3;
                    gsrc = Ap[p] + (size_t)(m0 + row)*K + k0 + ((slot ^ ((row>>1)&3)) << 3);
                } else {
                    int q2 = q - CA;
                    int p = q2 / (BN*4), qq = q2 % (BN*4);
                    int row = qq >> 2, slot = qq & 3;
                    gsrc = Bp[p] + (size_t)(n0 + row)*K + k0 + ((slot ^ ((row>>1)&3)) << 3);
                }
                gload_lds16(gsrc, L + (size_t)q*16);
            }
        }
    };

    stage(0, 0);
    __syncthreads();
    int cur = 0;
    constexpr int PI[6] = {0,0,1,0,1,2};
    constexpr int PJ[6] = {0,1,0,2,1,0};
    for (int t = 0; t < NT; ++t) {
        if (t + 1 < NT) stage(t + 1, cur ^ 1);
        const char* L = smem + (size_t)cur*SBUF;
        bf16x8 av[3][FM], bv[3][FN];
#pragma unroll
        for (int p = 0; p < 3; ++p) {
#pragma unroll
            for (int i = 0; i < FM; ++i) av[p][i] = *(const bf16x8*)(L + aoff[p][i]);
#pragma unroll
            for (int j = 0; j < FN; ++j) bv[p][j] = *(const bf16x8*)(L + boff[p][j]);
        }
#pragma unroll
        for (int t6 = 0; t6 < 6; ++t6)
#pragma unroll
            for (int i = 0; i < FM; ++i)
#pragma unroll
                for (int j = 0; j < FN; ++j)
                    acc[i][j] = __builtin_amdgcn_mfma_f32_16x16x32_bf16(
                        av[PI[t6]][i], bv[PJ[t6]][j], acc[i][j], 0, 0, 0);
        __syncthreads();
        cur ^= 1;
    }

    // epilogue: D layout col = lane&15, row = (lane>>4)*4 + q
#pragma unroll
    for (int i = 0; i < FM; ++i) {
        int rb = m0 + wr*(BM/WR) + i*16 + (hi << 2);
#pragma unroll
        for (int j = 0; j < FN; ++j) {
            int col = n0 + wc*(BN/WC) + j*16 + (lane & 15);
#pragma unroll
            for (int q = 0; q < 4; ++q) {
                int row = rb + q;
                float v = acc[i][j][q];
                if (TO_U) {
                    Uout[(size_t)row*NJ + col] = v;
                } else {
                    u16 h1,h2,h3; split3(v, h1,h2,h3);
                    size_t o = (size_t)row*IN_CH + col;
                    O1[o] = h1; O2[o] = h2; O3[o] = h3;
                    if ((row & (SEQ-1)) == SEQ-1)
                        outp[(size_t)((row >> 9)*OUT_SEQ + iter)*IN_CH + col] = v;
                }
            }
        }
    }
}

// ---------------- launch ----------------
extern "C" void kernel_launch(void* const* d_in, const int* in_sizes, int n_in,
                              void* d_out, int out_size, void* d_ws, size_t ws_size,
                              hipStream_t stream) {
    const float* x_in      = (const float*)d_in[0];
    const float* nu_log    = (const float*)d_in[1];
    const float* theta_log = (const float*)d_in[2];
    const float* gamma_log = (const float*)d_in[3];
    const float* B_re      = (const float*)d_in[4];
    const float* B_im      = (const float*)d_in[5];
    const float* C_re      = (const float*)d_in[6];
    const float* C_im      = (const float*)d_in[7];
    const float* D         = (const float*)d_in[8];
    float* out = (float*)d_out;

    char* ws = (char*)d_ws;
    float* U   = (float*)(ws + B_U);
    u16* Z1 = (u16*)(ws + B_Z);
    u16* Z2 = Z1 + (size_t)M_ROWS*NJ;
    u16* Z3 = Z2 + (size_t)M_ROWS*NJ;
    u16* XA1 = (u16*)(ws + B_XA);
    u16* XA2 = XA1 + (size_t)M_ROWS*IN_CH;
    u16* XA3 = XA2 + (size_t)M_ROWS*IN_CH;
    u16* XB1 = (u16*)(ws + B_XB);
    u16* XB2 = XB1 + (size_t)M_ROWS*IN_CH;
    u16* XB3 = XB2 + (size_t)M_ROWS*IN_CH;
    u16* WB  = (u16*)(ws + B_WB);
    u16* WCt = (u16*)(ws + B_WC);
    u16* WDt = (u16*)(ws + B_WD);
    float* lam = (float*)(ws + B_LAM);
    float* Hc  = (float*)(ws + B_HC);

    prep_lam_hc<<<1, 384, 0, stream>>>(nu_log, theta_log, lam, Hc);
    prep_wb<<<(NJ*IN_CH)/256, 256, 0, stream>>>(B_re, B_im, gamma_log, WB);
    prep_wcd<<<(IN_CH*NJ + IN_CH*IN_CH)/256, 256, 0, stream>>>(C_re, C_im, D, WCt, WDt);
    prep_x<<<(M_ROWS*IN_CH)/256, 256, 0, stream>>>(x_in, XA1, XA2, XA3);

    for (int it = 0; it < OUT_SEQ; ++it) {
        u16* Xc[3]; u16* Xn[3];
        if (it & 1) { Xc[0]=XB1; Xc[1]=XB2; Xc[2]=XB3; Xn[0]=XA1; Xn[1]=XA2; Xn[2]=XA3; }
        else        { Xc[0]=XA1; Xc[1]=XA2; Xc[2]=XA3; Xn[0]=XB1; Xn[1]=XB2; Xn[2]=XB3; }

        // GEMM1: U[4096][768] = sum_6 Xc_pi * WB_pj^T   (true K=256 -> S1=8)
        GArgs g1;
        for (int p = 0; p < 3; ++p) {
            g1.A1[p] = Xc[p];
            g1.B1[p] = WB + (size_t)p*NJ*IN_CH;
            g1.A2[p] = nullptr; g1.B2[p] = nullptr;
        }
        gemm3<64,64,2,2,8,0,true><<<dim3(M_ROWS/64, NJ/64), 256, 0, stream>>>(
            g1, U, nullptr, nullptr, nullptr, nullptr, 0);

        // scan
        scan_k<<<48, 64, 0, stream>>>(U, Z1, Z2, Z3, lam, Hc);

        // GEMM2: Xn[4096][256] = sum_6 Z_pi*WC_pj^T (K=768) + sum_6 Xc_pi*WD_pj^T (K=256)
        GArgs g2;
        u16* Zp[3] = {Z1, Z2, Z3};
        for (int p = 0; p < 3; ++p) {
            g2.A1[p] = Zp[p];
            g2.B1[p] = WCt + (size_t)p*IN_CH*NJ;
            g2.A2[p] = Xc[p];
            g2.B2[p] = WDt + (size_t)p*IN_CH*IN_CH;
        }
        gemm3<32,64,1,4,24,8,false><<<dim3(M_ROWS/32, IN_CH/64), 256, 0, stream>>>(
            g2, nullptr, Xn[0], Xn[1], Xn[2], out, it);
    }
}

// Round 4
// 2366.786 us; speedup vs baseline: 1.8822x; 1.5185x over previous
//
#include <hip/hip_runtime.h>
#include <hip/hip_bf16.h>
#include <math.h>

typedef unsigned short u16;
typedef __attribute__((ext_vector_type(8))) short bf16x8;
typedef __attribute__((ext_vector_type(4))) float f32x4;

#define IN_CH   256
#define STATE   384
#define OUT_SEQ 32
#define B_SZ    8
#define SEQ     512
#define M_ROWS  4096
#define NJ      768   // 2*STATE

// ---------------- workspace layout (bytes) ----------------
// U region (12.58MB) is reused as the 3 GEMM2 fp32 partials (3*4096*256*4 = same size)
static constexpr size_t B_U   = 0;
static constexpr size_t B_Z   = B_U  + (size_t)M_ROWS*NJ*4;
static constexpr size_t B_XA  = B_Z  + 3*(size_t)M_ROWS*NJ*2;
static constexpr size_t B_XB  = B_XA + 3*(size_t)M_ROWS*IN_CH*2;
static constexpr size_t B_WB  = B_XB + 3*(size_t)M_ROWS*IN_CH*2;
static constexpr size_t B_WC  = B_WB + 3*(size_t)NJ*IN_CH*2;
static constexpr size_t B_WD  = B_WC + 3*(size_t)IN_CH*NJ*2;
static constexpr size_t B_LAM = B_WD + 3*(size_t)IN_CH*IN_CH*2;  // lam 768f, lam64 768f
static constexpr size_t B_HC  = B_LAM + 2*768*4;                 // Hc0, Hc1: each 8*768 f
static constexpr size_t B_CAR = B_HC  + 2*(size_t)B_SZ*NJ*4;     // carries 8*8*768 f

// ---------------- helpers ----------------
__device__ __forceinline__ u16 f2b(float v) {
    __hip_bfloat16 h = __float2bfloat16(v);
    return *(u16*)&h;
}
__device__ __forceinline__ float b2f(u16 u) {
    __hip_bfloat16 h = *(__hip_bfloat16*)&u;
    return __bfloat162float(h);
}
__device__ __forceinline__ void split3(float v, u16& a, u16& b, u16& c) {
    a = f2b(v);  float r1 = v  - b2f(a);
    b = f2b(r1); float r2 = r1 - b2f(b);
    c = f2b(r2);
}
__device__ __forceinline__ void gload_lds16(const void* g, void* l) {
    __builtin_amdgcn_global_load_lds(
        (const __attribute__((address_space(1))) void*)g,
        (__attribute__((address_space(3))) void*)l, 16, 0, 0);
}

// ---------------- prep kernels ----------------
__global__ void prep_lam_hc(const float* __restrict__ nu_log,
                            const float* __restrict__ th_log,
                            float* __restrict__ lam, float* __restrict__ lam64,
                            float* __restrict__ hc0) {
    int n = threadIdx.x;
    if (n < STATE) {
        float lm = expf(-expf(nu_log[n]));
        float th = expf(th_log[n]);
        float ar = lm * cosf(th), ai = lm * sinf(th);
        lam[2*n] = ar; lam[2*n+1] = ai;
        float pr = ar, pi = ai;
#pragma unroll
        for (int i = 0; i < 6; ++i) {   // square 6x -> lambda^64
            float nr = pr*pr - pi*pi, ni = 2.f*pr*pi;
            pr = nr; pi = ni;
        }
        lam64[2*n] = pr; lam64[2*n+1] = pi;
    }
    for (int i = threadIdx.x; i < B_SZ*NJ; i += blockDim.x) hc0[i] = 0.f;
}

__global__ void prep_wb(const float* __restrict__ B_re, const float* __restrict__ B_im,
                        const float* __restrict__ gamma_log, u16* __restrict__ W) {
    int idx = blockIdx.x*blockDim.x + threadIdx.x;   // < 768*256
    int j = idx >> 8, c = idx & 255, n = j >> 1;
    float g = expf(gamma_log[n]);
    float v = g * ((j & 1) ? B_im[n*IN_CH + c] : B_re[n*IN_CH + c]);
    u16 a,b,cc; split3(v,a,b,cc);
    W[idx] = a; W[idx + NJ*IN_CH] = b; W[idx + 2*NJ*IN_CH] = cc;
}

__global__ void prep_wcd(const float* __restrict__ C_re, const float* __restrict__ C_im,
                         const float* __restrict__ D,
                         u16* __restrict__ WC, u16* __restrict__ WD) {
    int idx = blockIdx.x*blockDim.x + threadIdx.x;
    if (idx < IN_CH*NJ) {
        int o = idx / NJ, j = idx % NJ, n = j >> 1;
        float v = (j & 1) ? -C_im[o*STATE + n] : C_re[o*STATE + n];
        u16 a,b,c; split3(v,a,b,c);
        WC[idx] = a; WC[idx + IN_CH*NJ] = b; WC[idx + 2*IN_CH*NJ] = c;
    } else {
        int k = idx - IN_CH*NJ;
        float v = D[k];
        u16 a,b,c; split3(v,a,b,c);
        WD[k] = a; WD[k + IN_CH*IN_CH] = b; WD[k + 2*IN_CH*IN_CH] = c;
    }
}

__global__ void prep_x(const float* __restrict__ x,
                       u16* __restrict__ X1, u16* __restrict__ X2, u16* __restrict__ X3) {
    int idx = blockIdx.x*blockDim.x + threadIdx.x;
    u16 a,b,c; split3(x[idx],a,b,c);
    X1[idx] = a; X2[idx] = b; X3[idx] = c;
}

// ---------------- chunked scan: pass 1 (local carries) ----------------
// 384 blocks x 64 thr: block = (b, n-group g, chunk c); local 64-step scan from h=0.
__global__ __launch_bounds__(64)
void scan_carry(const float* __restrict__ Uf, const float* __restrict__ lam,
                float2* __restrict__ carry) {
    int bx = blockIdx.x;
    int b = bx / 48, rem = bx % 48, g = rem >> 3, c = rem & 7;
    int n = g*64 + threadIdx.x;
    float lre = lam[2*n], lim = lam[2*n+1];
    const float2* U2 = (const float2*)Uf + ((size_t)(b*SEQ + c*64))*STATE + n;
    float hre = 0.f, him = 0.f;
    float2 buf[16];
#pragma unroll
    for (int p = 0; p < 16; ++p) buf[p] = U2[(size_t)p*STATE];
    for (int s0 = 0; s0 < 64; s0 += 16) {
#pragma unroll
        for (int p = 0; p < 16; ++p) {
            int s = s0 + p;
            float ur = buf[p].x, ui = buf[p].y;
            if (s + 16 < 64) buf[p] = U2[(size_t)(s+16)*STATE];
            float nr = fmaf(lre, hre, fmaf(-lim, him, ur));
            float ni = fmaf(lre, him, fmaf( lim, hre, ui));
            hre = nr; him = ni;
        }
    }
    carry[(size_t)(b*8 + c)*STATE + n] = make_float2(hre, him);
}

// ---------------- chunked scan: pass 2 (prefix + emit splits) ----------------
__global__ __launch_bounds__(64)
void scan_emit(const float* __restrict__ Uf,
               u16* __restrict__ Z1, u16* __restrict__ Z2, u16* __restrict__ Z3,
               const float* __restrict__ lam, const float* __restrict__ lam64,
               const float2* __restrict__ carry,
               const float2* __restrict__ HcIn, float2* __restrict__ HcOut) {
    int bx = blockIdx.x;
    int b = bx / 48, rem = bx % 48, g = rem >> 3, c = rem & 7;
    int n = g*64 + threadIdx.x;
    float lre = lam[2*n], lim = lam[2*n+1];
    float p64r = lam64[2*n], p64i = lam64[2*n+1];
    float2 h = HcIn[(size_t)b*STATE + n];
    for (int j = 0; j < c; ++j) {
        float2 cj = carry[(size_t)(b*8 + j)*STATE + n];
        float nr = fmaf(p64r, h.x, fmaf(-p64i, h.y, cj.x));
        float ni = fmaf(p64r, h.y, fmaf( p64i, h.x, cj.y));
        h.x = nr; h.y = ni;
    }
    const float2* U2 = (const float2*)Uf + ((size_t)(b*SEQ + c*64))*STATE + n;
    size_t zb = (size_t)(b*SEQ + c*64)*NJ + 2*n;
    float2 buf[16];
#pragma unroll
    for (int p = 0; p < 16; ++p) buf[p] = U2[(size_t)p*STATE];
    for (int s0 = 0; s0 < 64; s0 += 16) {
#pragma unroll
        for (int p = 0; p < 16; ++p) {
            int s = s0 + p;
            float ur = buf[p].x, ui = buf[p].y;
            if (s + 16 < 64) buf[p] = U2[(size_t)(s+16)*STATE];
            float nr = fmaf(lre, h.x, fmaf(-lim, h.y, ur));
            float ni = fmaf(lre, h.y, fmaf( lim, h.x, ui));
            h.x = nr; h.y = ni;
            u16 a1,a2,a3, c1,c2,c3;
            split3(nr, a1,a2,a3);
            split3(ni, c1,c2,c3);
            size_t zo = zb + (size_t)s*NJ;
            ushort2 t;
            t.x = a1; t.y = c1; *(ushort2*)(Z1 + zo) = t;
            t.x = a2; t.y = c2; *(ushort2*)(Z2 + zo) = t;
            t.x = a3; t.y = c3; *(ushort2*)(Z3 + zo) = t;
        }
    }
    if (c == 7) HcOut[(size_t)b*STATE + n] = h;
}

// ---------------- unified 64x64 triple-plane MFMA GEMM ----------------
// out[m][col] (fp32, stride outs) = sum over 6 plane-pairs of A_pi * B_pj^T
// A row-major [M][sA] (bf16 planes), B transposed [ncols][sB]. BK=32.
struct GP {
    const u16* A[3]; const u16* B[3];
    int sA, sB, nt;
    float* out; int outs;
};

__global__ __launch_bounds__(256)
void gemm_m(GP q0, GP q1, GP q2) {
    GP q = (blockIdx.z == 0) ? q0 : ((blockIdx.z == 1) ? q1 : q2);
    constexpr int BM = 64, BN = 64;
    constexpr int PA = BM*64, PB = BN*64;      // bytes per LDS plane
    constexpr int SBUF = 3*(PA+PB);            // 24KB per buffer
    __shared__ __align__(16) char smem[2*SBUF];
    const int tid = threadIdx.x, lane = tid & 63, w = tid >> 6;
    const int wr = w & 1, wc = w >> 1;
    const int m0 = blockIdx.x*BM, n0 = blockIdx.y*BN;
    const int hi = lane >> 4, r16 = lane & 15;

    f32x4 acc[2][2];
#pragma unroll
    for (int i = 0; i < 2; ++i)
#pragma unroll
        for (int j = 0; j < 2; ++j) acc[i][j] = 0.f;

    int aoff[3][2], boff[3][2];
#pragma unroll
    for (int p = 0; p < 3; ++p) {
#pragma unroll
        for (int i = 0; i < 2; ++i) {
            int row = wr*32 + i*16 + r16;
            aoff[p][i] = p*PA + row*64 + ((hi ^ ((row>>1)&3)) << 4);
        }
#pragma unroll
        for (int j = 0; j < 2; ++j) {
            int row = wc*32 + j*16 + r16;
            boff[p][j] = 3*PA + p*PB + row*64 + ((hi ^ ((row>>1)&3)) << 4);
        }
    }

    auto stage = [&](int t, int buf) {
        int k0 = t*32;
        char* L = smem + (size_t)buf*SBUF;
#pragma unroll
        for (int r = 0; r < 6; ++r) {          // 1536 chunks of 16B
            int qc = tid + r*256;
            const u16* gsrc;
            if (qc < 768) {
                int p = qc >> 8, qq = qc & 255;
                int row = qq >> 2, slot = qq & 3;
                gsrc = q.A[p] + (size_t)(m0 + row)*q.sA + k0 + ((slot ^ ((row>>1)&3)) << 3);
            } else {
                int q2 = qc - 768;
                int p = q2 >> 8, qq = q2 & 255;
                int row = qq >> 2, slot = qq & 3;
                gsrc = q.B[p] + (size_t)(n0 + row)*q.sB + k0 + ((slot ^ ((row>>1)&3)) << 3);
            }
            gload_lds16(gsrc, L + (size_t)qc*16);
        }
    };

    stage(0, 0);
    __syncthreads();
    int cur = 0;
    constexpr int PI[6] = {0,0,1,0,1,2};
    constexpr int PJ[6] = {0,1,0,2,1,0};
    for (int t = 0; t < q.nt; ++t) {
        if (t + 1 < q.nt) stage(t + 1, cur ^ 1);
        const char* L = smem + (size_t)cur*SBUF;
        bf16x8 av[3][2], bv[3][2];
#pragma unroll
        for (int p = 0; p < 3; ++p) {
#pragma unroll
            for (int i = 0; i < 2; ++i) av[p][i] = *(const bf16x8*)(L + aoff[p][i]);
#pragma unroll
            for (int j = 0; j < 2; ++j) bv[p][j] = *(const bf16x8*)(L + boff[p][j]);
        }
#pragma unroll
        for (int t6 = 0; t6 < 6; ++t6)
#pragma unroll
            for (int i = 0; i < 2; ++i)
#pragma unroll
                for (int j = 0; j < 2; ++j)
                    acc[i][j] = __builtin_amdgcn_mfma_f32_16x16x32_bf16(
                        av[PI[t6]][i], bv[PJ[t6]][j], acc[i][j], 0, 0, 0);
        __syncthreads();
        cur ^= 1;
    }

    // epilogue: fp32 store; D layout col = lane&15, row = (lane>>4)*4 + e
#pragma unroll
    for (int i = 0; i < 2; ++i) {
        int rb = m0 + wr*32 + i*16 + (hi << 2);
#pragma unroll
        for (int j = 0; j < 2; ++j) {
            int col = n0 + wc*32 + j*16 + r16;
#pragma unroll
            for (int e = 0; e < 4; ++e)
                q.out[(size_t)(rb + e)*q.outs + col] = acc[i][j][e];
        }
    }
}

// ---------------- combine GEMM2 partials: sum -> split3 planes + out ----------------
__global__ __launch_bounds__(256)
void combine_k(const float* __restrict__ P,
               u16* __restrict__ O1, u16* __restrict__ O2, u16* __restrict__ O3,
               float* __restrict__ outp, int iter) {
    int idx = blockIdx.x*256 + threadIdx.x;     // 0..262143 (f32x4 units)
    const f32x4* P4 = (const f32x4*)P;
    f32x4 v = P4[idx];
    f32x4 v1 = P4[idx + 262144];
    f32x4 v2 = P4[idx + 2*262144];
    v = v + v1 + v2;
    ushort4 o1, o2, o3;
    u16 a,b,c;
    split3(v[0],a,b,c); o1.x=a; o2.x=b; o3.x=c;
    split3(v[1],a,b,c); o1.y=a; o2.y=b; o3.y=c;
    split3(v[2],a,b,c); o1.z=a; o2.z=b; o3.z=c;
    split3(v[3],a,b,c); o1.w=a; o2.w=b; o3.w=c;
    ((ushort4*)O1)[idx] = o1;
    ((ushort4*)O2)[idx] = o2;
    ((ushort4*)O3)[idx] = o3;
    int row = idx >> 6;
    if ((row & (SEQ-1)) == SEQ-1) {
        int col = (idx & 63) << 2;
        *(float4*)&outp[(size_t)((row >> 9)*OUT_SEQ + iter)*IN_CH + col] =
            make_float4(v[0], v[1], v[2], v[3]);
    }
}

// ---------------- launch ----------------
extern "C" void kernel_launch(void* const* d_in, const int* in_sizes, int n_in,
                              void* d_out, int out_size, void* d_ws, size_t ws_size,
                              hipStream_t stream) {
    const float* x_in      = (const float*)d_in[0];
    const float* nu_log    = (const float*)d_in[1];
    const float* theta_log = (const float*)d_in[2];
    const float* gamma_log = (const float*)d_in[3];
    const float* B_re      = (const float*)d_in[4];
    const float* B_im      = (const float*)d_in[5];
    const float* C_re      = (const float*)d_in[6];
    const float* C_im      = (const float*)d_in[7];
    const float* D         = (const float*)d_in[8];
    float* out = (float*)d_out;

    char* ws = (char*)d_ws;
    float* U   = (float*)(ws + B_U);     // also the 3 GEMM2 partials
    u16* Z1 = (u16*)(ws + B_Z);
    u16* Z2 = Z1 + (size_t)M_ROWS*NJ;
    u16* Z3 = Z2 + (size_t)M_ROWS*NJ;
    u16* XA1 = (u16*)(ws + B_XA);
    u16* XA2 = XA1 + (size_t)M_ROWS*IN_CH;
    u16* XA3 = XA2 + (size_t)M_ROWS*IN_CH;
    u16* XB1 = (u16*)(ws + B_XB);
    u16* XB2 = XB1 + (size_t)M_ROWS*IN_CH;
    u16* XB3 = XB2 + (size_t)M_ROWS*IN_CH;
    u16* WB  = (u16*)(ws + B_WB);
    u16* WCt = (u16*)(ws + B_WC);
    u16* WDt = (u16*)(ws + B_WD);
    float* lam   = (float*)(ws + B_LAM);
    float* lam64 = lam + 768;
    float2* Hc0  = (float2*)(ws + B_HC);
    float2* Hc1  = Hc0 + (size_t)B_SZ*STATE;
    float2* carry = (float2*)(ws + B_CAR);

    prep_lam_hc<<<1, 384, 0, stream>>>(nu_log, theta_log, lam, lam64, (float*)Hc0);
    prep_wb<<<(NJ*IN_CH)/256, 256, 0, stream>>>(B_re, B_im, gamma_log, WB);
    prep_wcd<<<(IN_CH*NJ + IN_CH*IN_CH)/256, 256, 0, stream>>>(C_re, C_im, D, WCt, WDt);
    prep_x<<<(M_ROWS*IN_CH)/256, 256, 0, stream>>>(x_in, XA1, XA2, XA3);

    for (int it = 0; it < OUT_SEQ; ++it) {
        u16* Xc[3]; u16* Xn[3];
        if (it & 1) { Xc[0]=XB1; Xc[1]=XB2; Xc[2]=XB3; Xn[0]=XA1; Xn[1]=XA2; Xn[2]=XA3; }
        else        { Xc[0]=XA1; Xc[1]=XA2; Xc[2]=XA3; Xn[0]=XB1; Xn[1]=XB2; Xn[2]=XB3; }
        float2* Hin  = (it & 1) ? Hc1 : Hc0;
        float2* Hout = (it & 1) ? Hc0 : Hc1;

        // GEMM1: U[4096][768] = sum_6 Xc_pi * WB_pj^T   (K=256, nt=8)
        GP g1;
        for (int p = 0; p < 3; ++p) {
            g1.A[p] = Xc[p];
            g1.B[p] = WB + (size_t)p*NJ*IN_CH;
        }
        g1.sA = IN_CH; g1.sB = IN_CH; g1.nt = 8; g1.out = U; g1.outs = NJ;
        gemm_m<<<dim3(M_ROWS/64, NJ/64, 1), 256, 0, stream>>>(g1, g1, g1);

        // scan (chunked): carries then emit
        scan_carry<<<384, 64, 0, stream>>>(U, lam, carry);
        scan_emit<<<384, 64, 0, stream>>>(U, Z1, Z2, Z3, lam, lam64, carry, Hin, Hout);

        // GEMM2 split-K: part0 Z[:,0:384), part1 Z[:,384:768), part2 X (K=256)
        u16* Zp[3] = {Z1, Z2, Z3};
        GP p0, p1, p2;
        for (int p = 0; p < 3; ++p) {
            p0.A[p] = Zp[p];        p0.B[p] = WCt + (size_t)p*IN_CH*NJ;
            p1.A[p] = Zp[p] + 384;  p1.B[p] = WCt + (size_t)p*IN_CH*NJ + 384;
            p2.A[p] = Xc[p];        p2.B[p] = WDt + (size_t)p*IN_CH*IN_CH;
        }
        p0.sA = NJ;    p0.sB = NJ;    p0.nt = 12; p0.out = U;               p0.outs = IN_CH;
        p1.sA = NJ;    p1.sB = NJ;    p1.nt = 12; p1.out = U + 1048576;     p1.outs = IN_CH;
        p2.sA = IN_CH; p2.sB = IN_CH; p2.nt = 8;  p2.out = U + 2*1048576;   p2.outs = IN_CH;
        gemm_m<<<dim3(M_ROWS/64, IN_CH/64, 3), 256, 0, stream>>>(p0, p1, p2);

        // combine partials -> Xn splits + out row
        combine_k<<<1024, 256, 0, stream>>>(U, Xn[0], Xn[1], Xn[2], out, it);
    }
}

// Round 5
// 2133.124 us; speedup vs baseline: 2.0883x; 1.1095x over previous
//
#include <hip/hip_runtime.h>
#include <hip/hip_bf16.h>
#include <math.h>

typedef unsigned short u16;
typedef __attribute__((ext_vector_type(8))) short bf16x8;
typedef __attribute__((ext_vector_type(4))) float f32x4;
typedef __attribute__((ext_vector_type(16))) float f32x16;

#define IN_CH   256
#define STATE   384
#define OUT_SEQ 32
#define B_SZ    8
#define SEQ     512
#define M_ROWS  4096
#define NJ      768   // 2*STATE

// ---------------- workspace layout (bytes) ----------------
// B_U region: holds U fp32 [4096][768] (12.58MB) for gemm1/emit, then is
// reused as 4 GEMM2 fp32 partials (4*4096*256*4 = 16.78MB). Sized for the max.
static constexpr size_t B_U   = 0;
static constexpr size_t B_Z   = B_U  + 4*(size_t)M_ROWS*IN_CH*4;     // 16.78MB
static constexpr size_t B_XA  = B_Z  + 3*(size_t)M_ROWS*NJ*2;
static constexpr size_t B_XB  = B_XA + 3*(size_t)M_ROWS*IN_CH*2;
static constexpr size_t B_WB  = B_XB + 3*(size_t)M_ROWS*IN_CH*2;
static constexpr size_t B_WC  = B_WB + 3*(size_t)NJ*IN_CH*2;
static constexpr size_t B_WD  = B_WC + 3*(size_t)IN_CH*NJ*2;
static constexpr size_t B_LAM = B_WD + 3*(size_t)IN_CH*IN_CH*2;      // lam, lam64
static constexpr size_t B_HC  = B_LAM + 2*768*4;                     // Hc0, Hc1
static constexpr size_t B_CAR = B_HC  + 2*(size_t)B_SZ*NJ*4;         // carries 64*384 f2

// ---------------- helpers ----------------
__device__ __forceinline__ u16 f2b(float v) {
    __hip_bfloat16 h = __float2bfloat16(v);
    return *(u16*)&h;
}
__device__ __forceinline__ float b2f(u16 u) {
    __hip_bfloat16 h = *(__hip_bfloat16*)&u;
    return __bfloat162float(h);
}
__device__ __forceinline__ void split3(float v, u16& a, u16& b, u16& c) {
    a = f2b(v);  float r1 = v  - b2f(a);
    b = f2b(r1); float r2 = r1 - b2f(b);
    c = f2b(r2);
}
__device__ __forceinline__ void gload_lds16(const void* g, void* l) {
    __builtin_amdgcn_global_load_lds(
        (const __attribute__((address_space(1))) void*)g,
        (__attribute__((address_space(3))) void*)l, 16, 0, 0);
}

// ---------------- prep kernels ----------------
__global__ void prep_lam_hc(const float* __restrict__ nu_log,
                            const float* __restrict__ th_log,
                            float* __restrict__ lam, float* __restrict__ lam64,
                            float* __restrict__ hc0) {
    int n = threadIdx.x;
    if (n < STATE) {
        float lm = expf(-expf(nu_log[n]));
        float th = expf(th_log[n]);
        float ar = lm * cosf(th), ai = lm * sinf(th);
        lam[2*n] = ar; lam[2*n+1] = ai;
        float pr = ar, pi = ai;
#pragma unroll
        for (int i = 0; i < 6; ++i) {   // lambda^64
            float nr = pr*pr - pi*pi, ni = 2.f*pr*pi;
            pr = nr; pi = ni;
        }
        lam64[2*n] = pr; lam64[2*n+1] = pi;
    }
    for (int i = threadIdx.x; i < B_SZ*NJ; i += blockDim.x) hc0[i] = 0.f;
}

// WB planes: W[p][j][c] = split_p(gamma_n * B_{re/im}[n][c]), j=2n+f, [768][256]
__global__ void prep_wb(const float* __restrict__ B_re, const float* __restrict__ B_im,
                        const float* __restrict__ gamma_log, u16* __restrict__ W) {
    int idx = blockIdx.x*blockDim.x + threadIdx.x;   // < 768*256
    int j = idx >> 8, c = idx & 255, n = j >> 1;
    float g = expf(gamma_log[n]);
    float v = g * ((j & 1) ? B_im[n*IN_CH + c] : B_re[n*IN_CH + c]);
    u16 a,b,cc; split3(v,a,b,cc);
    W[idx] = a; W[idx + NJ*IN_CH] = b; W[idx + 2*NJ*IN_CH] = cc;
}

__global__ void prep_wcd(const float* __restrict__ C_re, const float* __restrict__ C_im,
                         const float* __restrict__ D,
                         u16* __restrict__ WC, u16* __restrict__ WD) {
    int idx = blockIdx.x*blockDim.x + threadIdx.x;
    if (idx < IN_CH*NJ) {
        int o = idx / NJ, j = idx % NJ, n = j >> 1;
        float v = (j & 1) ? -C_im[o*STATE + n] : C_re[o*STATE + n];
        u16 a,b,c; split3(v,a,b,c);
        WC[idx] = a; WC[idx + IN_CH*NJ] = b; WC[idx + 2*IN_CH*NJ] = c;
    } else {
        int k = idx - IN_CH*NJ;
        float v = D[k];
        u16 a,b,c; split3(v,a,b,c);
        WD[k] = a; WD[k + IN_CH*IN_CH] = b; WD[k + 2*IN_CH*IN_CH] = c;
    }
}

__global__ void prep_x(const float* __restrict__ x,
                       u16* __restrict__ X1, u16* __restrict__ X2, u16* __restrict__ X3) {
    int idx = blockIdx.x*blockDim.x + threadIdx.x;
    u16 a,b,c; split3(x[idx],a,b,c);
    X1[idx] = a; X2[idx] = b; X3[idx] = c;
}

// ---------------- GEMM1: U = sum_6 X_pi * WB_pj^T, + fused chunk-carry scan ----
// 64x64 tile, 4 waves (2x2), 32x32x16 MFMA, k-major LDS subtiling, nt=8 (K=256).
struct G1P { const u16* A[3]; };

__global__ __launch_bounds__(256)
void gemm1_k(G1P ga, const u16* __restrict__ WBp, float* __restrict__ Uout,
             const float* __restrict__ lam, float2* __restrict__ carry) {
    __shared__ __align__(16) char smem[49152];   // 2 x 24KB
    const int tid = threadIdx.x, lane = tid & 63, w = tid >> 6;
    const int wr = w & 1, wc = w >> 1;
    const int m0 = blockIdx.x*64, n0 = blockIdx.y*64;
    const int hi5 = lane >> 5, lo5 = lane & 31;

    f32x16 acc;
#pragma unroll
    for (int i = 0; i < 16; ++i) acc[i] = 0.f;

    auto stage = [&](int t, int buf) {
        int k0 = t*32;
        char* L = smem + buf*24576;
#pragma unroll
        for (int r = 0; r < 6; ++r) {            // 1536 chunks of 16B
            int q = tid + r*256;
            const u16* gsrc;
            if (q < 768) {                        // A planes: [o(4)][row(64)][16B]
                int p = q >> 8, c = q & 255, o = c >> 6, row = c & 63;
                gsrc = ga.A[p] + (size_t)(m0 + row)*IN_CH + k0 + o*8;
            } else {                              // B planes
                int q2 = q - 768;
                int p = q2 >> 8, c = q2 & 255, o = c >> 6, col = c & 63;
                gsrc = WBp + (size_t)p*(NJ*IN_CH) + (size_t)(n0 + col)*IN_CH + k0 + o*8;
            }
            gload_lds16(gsrc, L + (size_t)q*16);
        }
    };

    stage(0, 0);
    __syncthreads();
    int cur = 0;
    constexpr int PI[6] = {0,0,1,0,1,2};
    constexpr int PJ[6] = {0,1,0,2,1,0};
    for (int t = 0; t < 8; ++t) {
        if (t + 1 < 8) stage(t + 1, cur ^ 1);
        const char* L = smem + cur*24576;
        bf16x8 av[3][2], bv[3][2];
#pragma unroll
        for (int p = 0; p < 3; ++p)
#pragma unroll
            for (int h = 0; h < 2; ++h) {
                av[p][h] = *(const bf16x8*)(L + p*4096 + (2*h + hi5)*1024 + (wr*32 + lo5)*16);
                bv[p][h] = *(const bf16x8*)(L + 12288 + p*4096 + (2*h + hi5)*1024 + (wc*32 + lo5)*16);
            }
#pragma unroll
        for (int t6 = 0; t6 < 6; ++t6)
#pragma unroll
            for (int h = 0; h < 2; ++h)
                acc = __builtin_amdgcn_mfma_f32_32x32x16_bf16(
                    av[PI[t6]][h], bv[PJ[t6]][h], acc, 0, 0, 0);
        __syncthreads();
        cur ^= 1;
    }

    // epilogue: U to global + LDS tile; D layout col=lane&31, row=(reg&3)+8*(reg>>2)+4*hi5
    float* Ls = (float*)smem;                     // [64][64] fp32 = 16KB
#pragma unroll
    for (int reg = 0; reg < 16; ++reg) {
        int rl = wr*32 + (reg & 3) + 8*(reg >> 2) + 4*hi5;
        int cl = wc*32 + lo5;
        float v = acc[reg];
        Uout[(size_t)(m0 + rl)*NJ + n0 + cl] = v;
        Ls[rl*64 + cl] = v;
    }
    __syncthreads();

    // fused chunk carry: 32 threads, one per state in this n-slice, 64-step local scan
    if (tid < 32) {
        int b = m0 >> 9, ch = (m0 >> 6) & 7;
        int n = (n0 >> 1) + tid;
        float lre = lam[2*n], lim = lam[2*n+1];
        float hr = 0.f, hm = 0.f;
        const float2* L2 = (const float2*)smem;   // [64][32] float2
        float2 pf[8];
#pragma unroll
        for (int p = 0; p < 8; ++p) pf[p] = L2[p*32 + tid];
        for (int s0 = 0; s0 < 64; s0 += 8) {
#pragma unroll
            for (int p = 0; p < 8; ++p) {
                int s = s0 + p;
                float ur = pf[p].x, ui = pf[p].y;
                if (s + 8 < 64) pf[p] = L2[(s + 8)*32 + tid];
                float nr = fmaf(lre, hr, fmaf(-lim, hm, ur));
                float nm = fmaf(lre, hm, fmaf( lim, hr, ui));
                hr = nr; hm = nm;
            }
        }
        carry[(size_t)(b*8 + ch)*STATE + n] = make_float2(hr, hm);
    }
}

// ---------------- scan emit: prefix from carries, emit Z splits ----------------
__global__ __launch_bounds__(64)
void scan_emit(const float* __restrict__ Uf,
               u16* __restrict__ Z1, u16* __restrict__ Z2, u16* __restrict__ Z3,
               const float* __restrict__ lam, const float* __restrict__ lam64,
               const float2* __restrict__ carry,
               const float2* __restrict__ HcIn, float2* __restrict__ HcOut) {
    int bx = blockIdx.x;
    int b = bx / 48, rem = bx % 48, g = rem >> 3, c = rem & 7;
    int n = g*64 + threadIdx.x;
    float lre = lam[2*n], lim = lam[2*n+1];
    float p64r = lam64[2*n], p64i = lam64[2*n+1];
    float2 h = HcIn[(size_t)b*STATE + n];
    for (int j = 0; j < c; ++j) {
        float2 cj = carry[(size_t)(b*8 + j)*STATE + n];
        float nr = fmaf(p64r, h.x, fmaf(-p64i, h.y, cj.x));
        float ni = fmaf(p64r, h.y, fmaf( p64i, h.x, cj.y));
        h.x = nr; h.y = ni;
    }
    const float2* U2 = (const float2*)Uf + ((size_t)(b*SEQ + c*64))*STATE + n;
    size_t zb = (size_t)(b*SEQ + c*64)*NJ + 2*n;
    float2 buf[16];
#pragma unroll
    for (int p = 0; p < 16; ++p) buf[p] = U2[(size_t)p*STATE];
    for (int s0 = 0; s0 < 64; s0 += 16) {
#pragma unroll
        for (int p = 0; p < 16; ++p) {
            int s = s0 + p;
            float ur = buf[p].x, ui = buf[p].y;
            if (s + 16 < 64) buf[p] = U2[(size_t)(s+16)*STATE];
            float nr = fmaf(lre, h.x, fmaf(-lim, h.y, ur));
            float ni = fmaf(lre, h.y, fmaf( lim, h.x, ui));
            h.x = nr; h.y = ni;
            u16 a1,a2,a3, c1,c2,c3;
            split3(nr, a1,a2,a3);
            split3(ni, c1,c2,c3);
            size_t zo = zb + (size_t)s*NJ;
            ushort2 t;
            t.x = a1; t.y = c1; *(ushort2*)(Z1 + zo) = t;
            t.x = a2; t.y = c2; *(ushort2*)(Z2 + zo) = t;
            t.x = a3; t.y = c3; *(ushort2*)(Z3 + zo) = t;
        }
    }
    if (c == 7) HcOut[(size_t)b*STATE + n] = h;
}

// ---------------- GEMM2: split-K z=4 partials; 128x64 tile, 32x32x16 ----------
// z=0..2: Z planes (sA=768, K-part z*256..), B=WC planes (sB=768)
// z=3   : X planes (sA=256), B=WD planes (sB=256)
struct G2P { const u16* Z[3]; const u16* X[3]; const u16* WC; const u16* WD; float* P; };

__global__ __launch_bounds__(256)
void gemm2_k(G2P g) {
    __shared__ __align__(16) char smem[73728];   // 2 x 36KB
    const int tid = threadIdx.x, lane = tid & 63, w = tid >> 6;
    const int wr = w & 1, wc = w >> 1;
    const int m0 = blockIdx.x*128, n0 = blockIdx.y*64;
    const int z = blockIdx.z;
    const int hi5 = lane >> 5, lo5 = lane & 31;

    const u16* Ap[3]; const u16* Bp; int sA, sB, k0b, pBs;
    if (z < 3) {
        Ap[0]=g.Z[0]; Ap[1]=g.Z[1]; Ap[2]=g.Z[2];
        sA = NJ; k0b = z*256; Bp = g.WC; sB = NJ; pBs = IN_CH*NJ;
    } else {
        Ap[0]=g.X[0]; Ap[1]=g.X[1]; Ap[2]=g.X[2];
        sA = IN_CH; k0b = 0; Bp = g.WD; sB = IN_CH; pBs = IN_CH*IN_CH;
    }

    f32x16 acc[2];
#pragma unroll
    for (int f = 0; f < 2; ++f)
#pragma unroll
        for (int i = 0; i < 16; ++i) acc[f][i] = 0.f;

    auto stage = [&](int t, int buf) {
        int k0 = k0b + t*32;
        char* L = smem + buf*36864;
#pragma unroll
        for (int r = 0; r < 9; ++r) {            // 2304 chunks of 16B
            int q = tid + r*256;
            const u16* gsrc;
            if (q < 1536) {                       // A planes: [o(4)][row(128)][16B]
                int p = q >> 9, c = q & 511, o = c >> 7, row = c & 127;
                gsrc = Ap[p] + (size_t)(m0 + row)*sA + k0 + o*8;
            } else {                              // B planes: [o(4)][col(64)][16B]
                int q2 = q - 1536;
                int p = q2 >> 8, c = q2 & 255, o = c >> 6, col = c & 63;
                gsrc = Bp + (size_t)p*pBs + (size_t)(n0 + col)*sB + k0 + o*8;
            }
            gload_lds16(gsrc, L + (size_t)q*16);
        }
    };

    stage(0, 0);
    __syncthreads();
    int cur = 0;
    constexpr int PI[6] = {0,0,1,0,1,2};
    constexpr int PJ[6] = {0,1,0,2,1,0};
    for (int t = 0; t < 8; ++t) {
        if (t + 1 < 8) stage(t + 1, cur ^ 1);
        const char* L = smem + cur*36864;
        bf16x8 av[3][2][2], bv[3][2];
#pragma unroll
        for (int p = 0; p < 3; ++p)
#pragma unroll
            for (int h = 0; h < 2; ++h) {
#pragma unroll
                for (int f = 0; f < 2; ++f)
                    av[p][f][h] = *(const bf16x8*)(L + p*8192 + (2*h + hi5)*2048
                                                   + (wr*64 + f*32 + lo5)*16);
                bv[p][h] = *(const bf16x8*)(L + 24576 + p*4096 + (2*h + hi5)*1024
                                            + (wc*32 + lo5)*16);
            }
#pragma unroll
        for (int t6 = 0; t6 < 6; ++t6)
#pragma unroll
            for (int f = 0; f < 2; ++f)
#pragma unroll
                for (int h = 0; h < 2; ++h)
                    acc[f] = __builtin_amdgcn_mfma_f32_32x32x16_bf16(
                        av[PI[t6]][f][h], bv[PJ[t6]][h], acc[f], 0, 0, 0);
        __syncthreads();
        cur ^= 1;
    }

    // epilogue: fp32 partial
    float* P = g.P + (size_t)z*M_ROWS*IN_CH;
#pragma unroll
    for (int f = 0; f < 2; ++f)
#pragma unroll
        for (int reg = 0; reg < 16; ++reg) {
            int row = m0 + wr*64 + f*32 + (reg & 3) + 8*(reg >> 2) + 4*hi5;
            int col = n0 + wc*32 + lo5;
            P[(size_t)row*IN_CH + col] = acc[f][reg];
        }
}

// ---------------- combine 4 partials -> split3 planes + out row ----------------
__global__ __launch_bounds__(256)
void combine_k(const float* __restrict__ P,
               u16* __restrict__ O1, u16* __restrict__ O2, u16* __restrict__ O3,
               float* __restrict__ outp, int iter) {
    int idx = blockIdx.x*256 + threadIdx.x;     // 0..262143 (f32x4 units)
    const f32x4* P4 = (const f32x4*)P;
    f32x4 v = P4[idx] + P4[idx + 262144] + P4[idx + 2*262144] + P4[idx + 3*262144];
    ushort4 o1, o2, o3;
    u16 a,b,c;
    split3(v[0],a,b,c); o1.x=a; o2.x=b; o3.x=c;
    split3(v[1],a,b,c); o1.y=a; o2.y=b; o3.y=c;
    split3(v[2],a,b,c); o1.z=a; o2.z=b; o3.z=c;
    split3(v[3],a,b,c); o1.w=a; o2.w=b; o3.w=c;
    ((ushort4*)O1)[idx] = o1;
    ((ushort4*)O2)[idx] = o2;
    ((ushort4*)O3)[idx] = o3;
    int row = idx >> 6;
    if ((row & (SEQ-1)) == SEQ-1) {
        int col = (idx & 63) << 2;
        *(float4*)&outp[(size_t)((row >> 9)*OUT_SEQ + iter)*IN_CH + col] =
            make_float4(v[0], v[1], v[2], v[3]);
    }
}

// ---------------- launch ----------------
extern "C" void kernel_launch(void* const* d_in, const int* in_sizes, int n_in,
                              void* d_out, int out_size, void* d_ws, size_t ws_size,
                              hipStream_t stream) {
    const float* x_in      = (const float*)d_in[0];
    const float* nu_log    = (const float*)d_in[1];
    const float* theta_log = (const float*)d_in[2];
    const float* gamma_log = (const float*)d_in[3];
    const float* B_re      = (const float*)d_in[4];
    const float* B_im      = (const float*)d_in[5];
    const float* C_re      = (const float*)d_in[6];
    const float* C_im      = (const float*)d_in[7];
    const float* D         = (const float*)d_in[8];
    float* out = (float*)d_out;

    char* ws = (char*)d_ws;
    float* U   = (float*)(ws + B_U);     // first 12.58MB = U; full 16.78MB = partials
    u16* Z1 = (u16*)(ws + B_Z);
    u16* Z2 = Z1 + (size_t)M_ROWS*NJ;
    u16* Z3 = Z2 + (size_t)M_ROWS*NJ;
    u16* XA1 = (u16*)(ws + B_XA);
    u16* XA2 = XA1 + (size_t)M_ROWS*IN_CH;
    u16* XA3 = XA2 + (size_t)M_ROWS*IN_CH;
    u16* XB1 = (u16*)(ws + B_XB);
    u16* XB2 = XB1 + (size_t)M_ROWS*IN_CH;
    u16* XB3 = XB2 + (size_t)M_ROWS*IN_CH;
    u16* WB  = (u16*)(ws + B_WB);
    u16* WCt = (u16*)(ws + B_WC);
    u16* WDt = (u16*)(ws + B_WD);
    float* lam   = (float*)(ws + B_LAM);
    float* lam64 = lam + 768;
    float2* Hc0  = (float2*)(ws + B_HC);
    float2* Hc1  = Hc0 + (size_t)B_SZ*STATE;
    float2* carry = (float2*)(ws + B_CAR);

    prep_lam_hc<<<1, 384, 0, stream>>>(nu_log, theta_log, lam, lam64, (float*)Hc0);
    prep_wb<<<(NJ*IN_CH)/256, 256, 0, stream>>>(B_re, B_im, gamma_log, WB);
    prep_wcd<<<(IN_CH*NJ + IN_CH*IN_CH)/256, 256, 0, stream>>>(C_re, C_im, D, WCt, WDt);
    prep_x<<<(M_ROWS*IN_CH)/256, 256, 0, stream>>>(x_in, XA1, XA2, XA3);

    for (int it = 0; it < OUT_SEQ; ++it) {
        u16* Xc[3]; u16* Xn[3];
        if (it & 1) { Xc[0]=XB1; Xc[1]=XB2; Xc[2]=XB3; Xn[0]=XA1; Xn[1]=XA2; Xn[2]=XA3; }
        else        { Xc[0]=XA1; Xc[1]=XA2; Xc[2]=XA3; Xn[0]=XB1; Xn[1]=XB2; Xn[2]=XB3; }
        float2* Hin  = (it & 1) ? Hc1 : Hc0;
        float2* Hout = (it & 1) ? Hc0 : Hc1;

        // GEMM1 + fused chunk-carries
        G1P g1;
        for (int p = 0; p < 3; ++p) g1.A[p] = Xc[p];
        gemm1_k<<<dim3(M_ROWS/64, NJ/64), 256, 0, stream>>>(g1, WB, U, lam, carry);

        // scan emit (prefix from carries)
        scan_emit<<<384, 64, 0, stream>>>(U, Z1, Z2, Z3, lam, lam64, carry, Hin, Hout);

        // GEMM2 split-K partials
        G2P g2;
        g2.Z[0]=Z1; g2.Z[1]=Z2; g2.Z[2]=Z3;
        g2.X[0]=Xc[0]; g2.X[1]=Xc[1]; g2.X[2]=Xc[2];
        g2.WC = WCt; g2.WD = WDt; g2.P = U;
        gemm2_k<<<dim3(M_ROWS/128, IN_CH/64, 4), 256, 0, stream>>>(g2);

        // combine partials -> Xn splits + out row
        combine_k<<<1024, 256, 0, stream>>>(U, Xn[0], Xn[1], Xn[2], out, it);
    }
}